// Round 4
// baseline (54.726 us; speedup 1.0000x reference)
//
#include <hip/hip_runtime.h>
#include <math.h>

// Problem geometry (fixed by the reference):
//   pred, gt : [16, 32, 256, 256] float32
//   out[b] = (1/32) * sum_{c,h,w} bce(pred, 0.9*gt + 0.1/256)
// Identity: max(x,0) - x*t + log1p(exp(-|x|)) = log(1+exp(x)) - x*t   (exact)
// Factored: sum bce = ln2 * sum(log2(1+e^x)) - 0.9*sum(x*g) - (0.1/256)*sum(x)
//
// Single fused kernel: per-block sums folded cross-block via ONE packed
// integer atomic per block into ws[b]:
//   bits [0,40)  : fixed-point (2^-12) block sum   (block sums are >= 0:
//                  softplus(x) >= x*t for t in [0,1], summed stays >= 0;
//                  batch total ~1.5M*4096 = 2^32.5 << 2^40)
//   bits [40,..) : block-arrival count (+1 per block)
// The block seeing old>>40 == BPB-1 is last; it adds its own contribution
// to the returned old value and writes out[b]. Integer adds commute ->
// bit-deterministic across graph replays. ws re-zeroed each call by a
// 128-byte hipMemsetAsync graph node.

#define B_DIM 16
#define ELEMS_PER_BATCH (32 * 256 * 256)   // 2,097,152
#define BPB 128                            // blocks per batch
#define TPB 256                            // threads per block
#define FIX_SCALE 4096.0f                  // 2^12 fixed-point
#define SUM_MASK ((1ULL << 40) - 1)

__global__ __launch_bounds__(TPB) void bce_fused_kernel(
        const float* __restrict__ pred,
        const float* __restrict__ gt,
        unsigned long long* __restrict__ ws,
        float* __restrict__ out) {
    const int b   = blockIdx.x / BPB;
    const int blk = blockIdx.x % BPB;
    const long long base = (long long)b * ELEMS_PER_BATCH;

    const float4* __restrict__ p4 = (const float4*)(pred + base);
    const float4* __restrict__ g4 = (const float4*)(gt + base);

    const int per_block = (ELEMS_PER_BATCH / 4) / BPB;  // 4,096 float4
    const int start     = blk * per_block;
    const int end       = start + per_block;

    // dual accumulator sets -> independent FP add chains
    float sp0 = 0.f, sp1 = 0.f;   // sum log2(1+e^x)
    float xg0 = 0.f, xg1 = 0.f;   // sum x*g
    float xs0 = 0.f, xs1 = 0.f;   // sum x

    #pragma unroll 8
    for (int i = start + threadIdx.x; i < end; i += TPB) {
        float4 x = p4[i];
        float4 g = g4[i];
        float e0 = __expf(x.x);
        float e1 = __expf(x.y);
        float e2 = __expf(x.z);
        float e3 = __expf(x.w);
        sp0 += __log2f(1.0f + e0);
        sp1 += __log2f(1.0f + e1);
        sp0 += __log2f(1.0f + e2);
        sp1 += __log2f(1.0f + e3);
        xg0 = __builtin_fmaf(x.x, g.x, xg0);
        xg1 = __builtin_fmaf(x.y, g.y, xg1);
        xg0 = __builtin_fmaf(x.z, g.z, xg0);
        xg1 = __builtin_fmaf(x.w, g.w, xg1);
        xs0 += x.x + x.y;
        xs1 += x.z + x.w;
    }

    float acc = 0.6931471805599453f * (sp0 + sp1)
              - 0.9f               * (xg0 + xg1)
              - (0.1f / 256.0f)    * (xs0 + xs1);

    // wave-64 shuffle reduction
    #pragma unroll
    for (int off = 32; off > 0; off >>= 1)
        acc += __shfl_down(acc, off, 64);

    __shared__ float smem[TPB / 64];
    if ((threadIdx.x & 63) == 0) smem[threadIdx.x >> 6] = acc;
    __syncthreads();

    if (threadIdx.x == 0) {
        float s = smem[0] + smem[1] + smem[2] + smem[3];
        unsigned long long fixed =
            (unsigned long long)(s * FIX_SCALE + 0.5f);      // s >= 0
        unsigned long long pack = (1ULL << 40) | fixed;
        unsigned long long old  = atomicAdd(&ws[b], pack);
        if ((old >> 40) == (unsigned long long)(BPB - 1)) {
            unsigned long long tot = (old & SUM_MASK) + fixed;
            out[b] = (float)((double)tot * (1.0 / 4096.0) * (1.0 / 32.0));
        }
    }
}

extern "C" void kernel_launch(void* const* d_in, const int* in_sizes, int n_in,
                              void* d_out, int out_size, void* d_ws, size_t ws_size,
                              hipStream_t stream) {
    const float* pred = (const float*)d_in[0];
    const float* gt   = (const float*)d_in[1];
    float* out        = (float*)d_out;
    unsigned long long* ws = (unsigned long long*)d_ws;  // 16 * 8 = 128 B

    hipMemsetAsync(ws, 0, B_DIM * sizeof(unsigned long long), stream);
    bce_fused_kernel<<<B_DIM * BPB, TPB, 0, stream>>>(pred, gt, ws, out);
}

// Round 5
// 44.603 us; speedup vs baseline: 1.2270x; 1.2270x over previous
//
#include <hip/hip_runtime.h>
#include <math.h>

// Problem geometry (fixed by the reference):
//   pred, gt : [16, 32, 256, 256] float32
//   out[b] = (1/32) * sum_{c,h,w} bce(pred, 0.9*gt + 0.1/256)
// Identity: max(x,0) - x*t + log1p(exp(-|x|)) = log(1+exp(x)) - x*t   (exact)
// Factored: sum bce = ln2 * sum(log2(1+e^x)) - 0.9*sum(x*g) - (0.1/256)*sum(x)
//
// Two-kernel structure (round-3 best, 45.8us): fused single-kernel with a
// memset graph node REGRESSED to 54.7us (memset blit dispatch + dependency
// edge costs more than the tiny finalize launch).

#define B_DIM 16
#define ELEMS_PER_BATCH (32 * 256 * 256)   // 2,097,152
#define BPB 128                            // blocks per batch
#define TPB 256                            // threads per block

__global__ __launch_bounds__(TPB) void bce_partial_kernel(
        const float* __restrict__ pred,
        const float* __restrict__ gt,
        float* __restrict__ partials) {
    const int b   = blockIdx.x / BPB;
    const int blk = blockIdx.x % BPB;
    const long long base = (long long)b * ELEMS_PER_BATCH;

    const float4* __restrict__ p4 = (const float4*)(pred + base);
    const float4* __restrict__ g4 = (const float4*)(gt + base);

    const int per_block = (ELEMS_PER_BATCH / 4) / BPB;  // 4,096 float4
    const int start     = blk * per_block;

    // Each thread: 2 float4 per array per iteration (64B in flight/iter),
    // 8 iterations total. Dual accumulator sets -> independent add chains.
    float sp0 = 0.f, sp1 = 0.f;   // sum log2(1+e^x)
    float xg0 = 0.f, xg1 = 0.f;   // sum x*g
    float xs0 = 0.f, xs1 = 0.f;   // sum x

    #pragma unroll
    for (int it = 0; it < 8; ++it) {
        const int i0 = start + it * (2 * TPB) + threadIdx.x;
        const int i1 = i0 + TPB;
        float4 xa = p4[i0];
        float4 xb = p4[i1];
        float4 ga = g4[i0];
        float4 gb = g4[i1];

        sp0 += __log2f(1.0f + __expf(xa.x));
        sp1 += __log2f(1.0f + __expf(xa.y));
        sp0 += __log2f(1.0f + __expf(xa.z));
        sp1 += __log2f(1.0f + __expf(xa.w));
        sp0 += __log2f(1.0f + __expf(xb.x));
        sp1 += __log2f(1.0f + __expf(xb.y));
        sp0 += __log2f(1.0f + __expf(xb.z));
        sp1 += __log2f(1.0f + __expf(xb.w));

        xg0 = __builtin_fmaf(xa.x, ga.x, xg0);
        xg1 = __builtin_fmaf(xa.y, ga.y, xg1);
        xg0 = __builtin_fmaf(xa.z, ga.z, xg0);
        xg1 = __builtin_fmaf(xa.w, ga.w, xg1);
        xg0 = __builtin_fmaf(xb.x, gb.x, xg0);
        xg1 = __builtin_fmaf(xb.y, gb.y, xg1);
        xg0 = __builtin_fmaf(xb.z, gb.z, xg0);
        xg1 = __builtin_fmaf(xb.w, gb.w, xg1);

        xs0 += (xa.x + xa.y) + (xb.x + xb.y);
        xs1 += (xa.z + xa.w) + (xb.z + xb.w);
    }

    float acc = 0.6931471805599453f * (sp0 + sp1)
              - 0.9f               * (xg0 + xg1)
              - (0.1f / 256.0f)    * (xs0 + xs1);

    // wave-64 shuffle reduction
    #pragma unroll
    for (int off = 32; off > 0; off >>= 1)
        acc += __shfl_down(acc, off, 64);

    __shared__ float smem[TPB / 64];
    if ((threadIdx.x & 63) == 0) smem[threadIdx.x >> 6] = acc;
    __syncthreads();

    if (threadIdx.x == 0) {
        float s = smem[0] + smem[1] + smem[2] + smem[3];
        partials[b * BPB + blk] = s;
    }
}

__global__ __launch_bounds__(64) void bce_finalize_kernel(
        const float* __restrict__ partials,
        float* __restrict__ out) {
    const int b = blockIdx.x;
    float acc = 0.0f;
    for (int i = threadIdx.x; i < BPB; i += 64)
        acc += partials[b * BPB + i];
    #pragma unroll
    for (int off = 32; off > 0; off >>= 1)
        acc += __shfl_down(acc, off, 64);
    if (threadIdx.x == 0)
        out[b] = acc * (1.0f / 32.0f);   // mean over channels
}

extern "C" void kernel_launch(void* const* d_in, const int* in_sizes, int n_in,
                              void* d_out, int out_size, void* d_ws, size_t ws_size,
                              hipStream_t stream) {
    const float* pred = (const float*)d_in[0];
    const float* gt   = (const float*)d_in[1];
    float* out        = (float*)d_out;
    float* partials   = (float*)d_ws;    // needs 16*128*4 = 8 KB

    bce_partial_kernel<<<B_DIM * BPB, TPB, 0, stream>>>(pred, gt, partials);
    bce_finalize_kernel<<<B_DIM, 64, 0, stream>>>(partials, out);
}